// Round 7
// baseline (226.662 us; speedup 1.0000x reference)
//
#include <hip/hip_runtime.h>
#include <hip/hip_bf16.h>
#include <math.h>

typedef short bf16x8 __attribute__((ext_vector_type(8)));
typedef float f32x4 __attribute__((ext_vector_type(4)));

#define KDIM 768
#define NTAG 10000
#define NVOC 21128
#define HID 256
#define NTOK 4096
#define NCHUNK 24
#define CHUNK 881                 // ceil(21128/24)
#define NTILE 56                  // ceil(881/16)
#define M0 4.0f                   // fixed softmax shift (logits ~N(0,0.55))
#define WMSCALE 16.0f             // Wm pre-scale (fp8 subnormal avoidance)
#define INVSCALE 0.0625f

// ws layout (bytes)
#define WS_A     0ull                    // fp8  [4096][768] title          (3145728)
#define WS_AVID  3145728ull              // bf16 [32][768] video            (49152)
#define WS_PSUM  3194880ull              // f32  [4096][24]                 (393216)
#define WS_GOLD  3588096ull              // f32  [4096]                     (16384)
#define WS_TAGL  3604480ull              // f32  [1] atomic                 (64)
#define WS_WM8   3604544ull              // fp8  [21128][768], x16 scaled   (16226304)
#define WS_NEED  (WS_WM8 + 16226304ull + 65536ull)   // + OOB staging pad

#define OUT_EMB  320000
#define OUT_LTAG 328192
#define OUT_LMLM 328193

#define TAG_BLKS 313
#define GOLD_BLKS 1024
#define EMB_BLKS 32

typedef const __attribute__((address_space(1))) unsigned int glds_g;
typedef __attribute__((address_space(3))) unsigned int glds_l;

static __device__ __forceinline__ unsigned short f2bf(float f) {
  unsigned u = __builtin_bit_cast(unsigned, f);
  u = u + 0x7FFFu + ((u >> 16) & 1u);
  return (unsigned short)(u >> 16);
}

// pack 4 floats -> 4 fp8 e4m3 bytes
static __device__ __forceinline__ int pk4_fp8(float4 v, float scale) {
  int w = __builtin_amdgcn_cvt_pk_fp8_f32(v.x * scale, v.y * scale, 0, false);
  w = __builtin_amdgcn_cvt_pk_fp8_f32(v.z * scale, v.w * scale, w, true);
  return w;
}

// ---------------- conversions: title->fp8, video->bf16, Wm->fp8(x16) ----------------
__global__ __launch_bounds__(256) void k_conv(
    const float* __restrict__ title, const float* __restrict__ video,
    const float* __restrict__ Wm,
    char* __restrict__ A8, unsigned short* __restrict__ Avid,
    char* __restrict__ Wm8, float* __restrict__ tagSum) {
  const int nT = 393216;            // title groups of 8 floats
  const int nV = 3072;              // video groups
  const int nW = 2028288;           // Wm groups
  int i = blockIdx.x * 256 + threadIdx.x;
  if (i == 0) tagSum[0] = 0.f;
  if (i < nT) {
    float4 v0 = ((const float4*)title)[i * 2];
    float4 v1 = ((const float4*)title)[i * 2 + 1];
    int2 o = {pk4_fp8(v0, 1.f), pk4_fp8(v1, 1.f)};
    *(int2*)(A8 + (size_t)i * 8) = o;
  } else if (i < nT + nV) {
    int j = i - nT;
    float4 v0 = ((const float4*)video)[j * 2];
    float4 v1 = ((const float4*)video)[j * 2 + 1];
    bf16x8 o;
    o[0] = (short)f2bf(v0.x); o[1] = (short)f2bf(v0.y);
    o[2] = (short)f2bf(v0.z); o[3] = (short)f2bf(v0.w);
    o[4] = (short)f2bf(v1.x); o[5] = (short)f2bf(v1.y);
    o[6] = (short)f2bf(v1.z); o[7] = (short)f2bf(v1.w);
    *(bf16x8*)(Avid + (size_t)j * 8) = o;
  } else {
    int j = i - nT - nV;
    if (j >= nW) return;
    float4 v0 = ((const float4*)Wm)[j * 2];
    float4 v1 = ((const float4*)Wm)[j * 2 + 1];
    int2 o = {pk4_fp8(v0, WMSCALE), pk4_fp8(v1, WMSCALE)};
    *(int2*)(Wm8 + (size_t)j * 8) = o;
  }
}

// ---------------- MLM GEMM (fp8) + streaming sum-exp ----------------
// grid 768: chunk = bid%24 (XCD c%8), mt = bid/24. 4 waves x 32 rows.
// A fragments pinned in VGPRs via opaque-asm (non-rematerializable defs).
// LDS B tile 12KB: byte = kk*512 + col*32 + g*8 -> per-instr 512B perfect pack,
//   zero bank conflicts; 16B granules = 16 contiguous fp8 of one row (gld_lds ok).
// Quad-buffer, depth-3 prefetch, ONE barrier per tile, vmcnt(6).
template<bool WM8>
__global__ __launch_bounds__(256)
__attribute__((amdgpu_waves_per_eu(3, 3)))
void k_mlm(
    const char* __restrict__ A8,
    const float* __restrict__ Wm,
    const char* __restrict__ Wm8,
    const float* __restrict__ bm,
    float* __restrict__ psum) {
  __shared__ __align__(1024) char Bsm[4][12288];              // 48 KiB quad
  __shared__ float biasS[NTILE * 16];                         // 3.5 KiB
  const int tid = threadIdx.x;
  const int lane = tid & 63, g = lane >> 4, col = lane & 15;
  const int wave = tid >> 6;
  const int chunk = blockIdx.x % NCHUNK, mt = blockIdx.x / NCHUNK;
  const int nbeg = chunk * CHUNK;
  const int nend = min(nbeg + CHUNK, NVOC);

  // A fragments (full K in registers, fp8: 2 VGPR each)
  const int arow0 = mt * 128 + wave * 32;
  long a0[24], a1[24];
  #pragma unroll
  for (int kk = 0; kk < 24; ++kk) {
    a0[kk] = *(const long*)(A8 + (size_t)(arow0 + col) * KDIM + kk * 32 + g * 8);
    a1[kk] = *(const long*)(A8 + (size_t)(arow0 + 16 + col) * KDIM + kk * 32 + g * 8);
  }
  // pin: opaque defs -> compiler cannot rematerialize the loads
  #pragma unroll
  for (int kk = 0; kk < 24; ++kk) {
    asm volatile("" : "+v"(a0[kk]));
    asm volatile("" : "+v"(a1[kk]));
  }

  // bias chunk -> LDS
  for (int i = tid; i < NTILE * 16; i += 256) {
    int n = nbeg + i;
    biasS[i] = (n < NVOC) ? bm[n] : 0.f;
  }

  float s[8];
  #pragma unroll
  for (int i = 0; i < 8; ++i) s[i] = 0.f;

  // staging source offsets: granule sg = j*256+tid (16B each):
  // row (sg>>1)&15, koff = (sg>>5)*32 + (sg&1)*16
  int e[3];
  #pragma unroll
  for (int j = 0; j < 3; ++j) {
    int sg = j * 256 + tid;
    e[j] = (((sg >> 1) & 15)) * KDIM + (sg >> 5) * 32 + (sg & 1) * 16;
  }

  const int off0 = col * 32 + g * 8;   // read base; loop offset kk*512

  auto COMPUTE = [&](int t) {
    const char* B = &Bsm[t & 3][0] + off0;
    f32x4 acc0 = {0.f, 0.f, 0.f, 0.f}, acc1 = {0.f, 0.f, 0.f, 0.f};
    #pragma unroll
    for (int kk = 0; kk < 24; ++kk) {
      long b = *(const long*)(B + kk * 512);
      acc0 = __builtin_amdgcn_mfma_f32_16x16x32_fp8_fp8(a0[kk], b, acc0, 0, 0, 0);
      acc1 = __builtin_amdgcn_mfma_f32_16x16x32_fp8_fp8(a1[kk], b, acc1, 0, 0, 0);
    }
    const int n0 = nbeg + t * 16;
    const bool valid = (n0 + col) < nend;
    const float bias = biasS[t * 16 + col];
    #pragma unroll
    for (int rr = 0; rr < 4; ++rr) {
      float x0 = acc0[rr] * INVSCALE + bias;
      float x1 = acc1[rr] * INVSCALE + bias;
      s[rr]     += valid ? __expf(x0 - M0) : 0.f;
      s[rr + 4] += valid ? __expf(x1 - M0) : 0.f;
    }
  };

  if constexpr (WM8) {
    auto STAGE = [&](int buf, int tt) {
      const char* src = Wm8 + (size_t)nbeg * KDIM + (size_t)tt * 12288;
      char* dst = &Bsm[buf][0] + wave * 1024;
      #pragma unroll
      for (int j = 0; j < 3; ++j) {
        __builtin_amdgcn_global_load_lds((glds_g*)(src + e[j]),
                                         (glds_l*)(dst + j * 4096), 16, 0, 0);
      }
    };
    STAGE(0, 0); STAGE(1, 1); STAGE(2, 2);                 // depth-3 prologue
    asm volatile("s_waitcnt lgkmcnt(0)" ::: "memory");     // bias ds_writes done
    for (int t = 0; t < NTILE; ++t) {
      asm volatile("s_waitcnt vmcnt(6)" ::: "memory");     // tile t staged
      __builtin_amdgcn_s_barrier();                        // all waves: t ready,
      __builtin_amdgcn_sched_barrier(0);                   //  t-1 reads done
      int tp = t + 3;
      STAGE((t + 3) & 3, (tp < NTILE) ? tp : 0);           // prefetch t+3
      __builtin_amdgcn_s_setprio(1);
      COMPUTE(t);
      __builtin_amdgcn_s_setprio(0);
      __builtin_amdgcn_sched_barrier(0);
    }
  } else {
    // fallback: serial staging from f32 Wm with inline fp8 cvt (x16)
    __syncthreads();
    for (int t = 0; t < NTILE; ++t) {
      #pragma unroll
      for (int j = 0; j < 3; ++j) {
        int sg = j * 256 + tid;
        int n = nbeg + t * 16 + ((sg >> 1) & 15);
        int koff = (sg >> 5) * 32 + (sg & 1) * 16;
        int4 o = {0, 0, 0, 0};
        if (n < NVOC) {
          const float* wp = Wm + (size_t)n * KDIM + koff;
          float4 f0 = ((const float4*)wp)[0], f1 = ((const float4*)wp)[1];
          float4 f2 = ((const float4*)wp)[2], f3 = ((const float4*)wp)[3];
          o.x = pk4_fp8(f0, WMSCALE); o.y = pk4_fp8(f1, WMSCALE);
          o.z = pk4_fp8(f2, WMSCALE); o.w = pk4_fp8(f3, WMSCALE);
        }
        *(int4*)(&Bsm[0][0] + sg * 16) = o;
      }
      __syncthreads();
      COMPUTE(t);
      __syncthreads();
    }
  }

  // combine the 16 col-owner lanes per row, write per-chunk partial sums
  #pragma unroll
  for (int i = 0; i < 8; ++i) {
    float v = s[i];
    v += __shfl_xor(v, 1);
    v += __shfl_xor(v, 2);
    v += __shfl_xor(v, 4);
    v += __shfl_xor(v, 8);
    s[i] = v;
  }
  if (col == 0) {
    #pragma unroll
    for (int mblk = 0; mblk < 2; ++mblk)
      #pragma unroll
      for (int rr = 0; rr < 4; ++rr) {
        int tok = arow0 + mblk * 16 + g * 4 + rr;
        psum[tok * NCHUNK + chunk] = s[mblk * 4 + rr];
      }
  }
}

// ---------------- fused tail: tag (0..312) | gold (313..1336) | embed (1337..1368) ----
__global__ __launch_bounds__(256) void k_tail(
    const unsigned short* __restrict__ Avid,
    const float* __restrict__ Wt, const float* __restrict__ bt,
    const float* __restrict__ ylab,
    const float* __restrict__ title, const int* __restrict__ lab,
    const float* __restrict__ Wm, const float* __restrict__ bm,
    const float* __restrict__ video,
    const float* __restrict__ Wh, const float* __restrict__ bh,
    float* __restrict__ out_sig, float* __restrict__ tagSum,
    float* __restrict__ gold, float* __restrict__ out_emb) {
  __shared__ __align__(1024) char smem[49664];
  const int bid = blockIdx.x, tid = threadIdx.x;
  const int wave = tid >> 6, lane = tid & 63, g = lane >> 4, col = lane & 15;

  if (bid < TAG_BLKS) {
    // ---- tag head: 2 ntiles/block, Wt staged coalesced -> bf16 LDS ----
    unsigned short* Bt = (unsigned short*)smem;       // [2][24 KiB]
    float* wsum = (float*)(smem + 49152);
    // stage: granule sg (16B): tile tt=sg/1536; within: kk=sg>>6, c=(sg&63)>>2, gg=sg&3
    #pragma unroll
    for (int j = 0; j < 12; ++j) {
      int sg = j * 256 + tid;
      int tt = (j >= 6) ? 1 : 0;
      int sgl = sg - tt * 1536;
      int kk = sgl >> 6, c = (sgl & 63) >> 2, gg = sgl & 3;
      int n = (bid * 2 + tt) * 16 + c;
      bf16x8 o = {};
      if (n < NTAG) {
        const float* wp = Wt + (size_t)n * KDIM + kk * 32 + gg * 8;
        float4 f0 = ((const float4*)wp)[0], f1 = ((const float4*)wp)[1];
        o[0] = (short)f2bf(f0.x); o[1] = (short)f2bf(f0.y);
        o[2] = (short)f2bf(f0.z); o[3] = (short)f2bf(f0.w);
        o[4] = (short)f2bf(f1.x); o[5] = (short)f2bf(f1.y);
        o[6] = (short)f2bf(f1.z); o[7] = (short)f2bf(f1.w);
      }
      *(bf16x8*)((char*)Bt + sg * 16) = o;
    }
    __syncthreads();

    const int ntile = bid * 2 + (wave >> 1), mhalf = wave & 1;
    float lacc = 0.f;
    if (ntile < 625) {
      bf16x8 a[24];
      #pragma unroll
      for (int kk = 0; kk < 24; ++kk)
        a[kk] = *(const bf16x8*)(Avid + (size_t)(mhalf * 16 + col) * KDIM + kk * 32 + g * 8);
      const char* Bb = (const char*)Bt + (wave >> 1) * 24576 + col * 64 + g * 16;
      f32x4 acc = {0.f, 0.f, 0.f, 0.f};
      #pragma unroll
      for (int kk = 0; kk < 24; ++kk) {
        bf16x8 b = *(const bf16x8*)(Bb + kk * 1024);
        acc = __builtin_amdgcn_mfma_f32_16x16x32_bf16(a[kk], b, acc, 0, 0, 0);
      }
      const int nc = ntile * 16 + col;
      if (nc < NTAG) {
        const float bias = bt[nc];
        #pragma unroll
        for (int rr = 0; rr < 4; ++rr) {
          int brow = mhalf * 16 + g * 4 + rr;
          float x = acc[rr] + bias;
          out_sig[(size_t)brow * NTAG + nc] = 1.f / (1.f + __expf(-x));
          float y = ylab[(size_t)brow * NTAG + nc];
          lacc += fmaxf(x, 0.f) - x * y + log1pf(__expf(-fabsf(x)));
        }
      }
    }
    #pragma unroll
    for (int m = 32; m; m >>= 1) lacc += __shfl_xor(lacc, m);
    if (lane == 0) wsum[wave] = lacc;
    __syncthreads();
    if (tid == 0) atomicAdd(tagSum, wsum[0] + wsum[1] + wsum[2] + wsum[3]);

  } else if (bid < TAG_BLKS + GOLD_BLKS) {
    // ---- gold logit per token (f32 exact) ----
    int tok = (bid - TAG_BLKS) * 4 + wave;
    int l = lab[tok];
    float acc = 0.f;
    #pragma unroll
    for (int j = 0; j < 12; ++j) {
      int k = j * 64 + lane;
      acc += title[(size_t)tok * KDIM + k] * Wm[(size_t)l * KDIM + k];
    }
    #pragma unroll
    for (int m = 32; m; m >>= 1) acc += __shfl_xor(acc, m);
    if (lane == 0) gold[tok] = acc + bm[l];

  } else {
    // ---- embedding head (f32 exact) ----
    float* feat = (float*)smem;
    float* red = (float*)(smem + 49152);
    const int b = bid - TAG_BLKS - GOLD_BLKS;
    #pragma unroll
    for (int j = 0; j < 6; ++j) {
      int k = j * 256 + tid;
      feat[k] = (k < KDIM) ? video[(size_t)b * KDIM + k]
                           : title[(size_t)b * 128 * KDIM + (k - KDIM)];
    }
    __syncthreads();
    float acc = bh[tid];
    #pragma unroll 8
    for (int k = 0; k < 1536; k += 4) {
      float4 w = *(const float4*)(Wh + (size_t)tid * 1536 + k);
      acc += w.x * feat[k] + w.y * feat[k + 1] + w.z * feat[k + 2] + w.w * feat[k + 3];
    }
    float ss = acc * acc;
    #pragma unroll
    for (int m = 32; m; m >>= 1) ss += __shfl_xor(ss, m);
    if (lane == 0) red[wave] = ss;
    __syncthreads();
    float nrm = sqrtf(red[0] + red[1] + red[2] + red[3]);
    float scale = 1.f / fmaxf(nrm, 1e-12f);
    out_emb[(size_t)b * HID + tid] = acc * scale;
  }
}

// ---------------- finalize losses ----------------
__global__ __launch_bounds__(256) void k_final(
    const float* __restrict__ psum, const float* __restrict__ gold,
    const int* __restrict__ lab, const float* __restrict__ tagSum,
    float* __restrict__ out) {
  __shared__ float red[4];
  const int tid = threadIdx.x, wave = tid >> 6, lane = tid & 63;
  if (tid == 0) out[OUT_LTAG] = tagSum[0] / 320000.f;

  float lm = 0.f;
  for (int tok = tid; tok < NTOK; tok += 256) {
    float S = 0.f;
    #pragma unroll
    for (int c = 0; c < NCHUNK; ++c) S += psum[tok * NCHUNK + c];
    float lse = M0 + logf(S);
    if (lab[tok] != 0) lm += lse - gold[tok];
  }
  #pragma unroll
  for (int m = 32; m; m >>= 1) lm += __shfl_xor(lm, m);
  if (lane == 0) red[wave] = lm;
  __syncthreads();
  if (tid == 0) out[OUT_LMLM] = red[0] + red[1] + red[2] + red[3];
}

extern "C" void kernel_launch(void* const* d_in, const int* in_sizes, int n_in,
                              void* d_out, int out_size, void* d_ws, size_t ws_size,
                              hipStream_t stream) {
  const float* video = (const float*)d_in[0];
  const float* title = (const float*)d_in[1];
  const float* ylab  = (const float*)d_in[2];
  const int*   lab   = (const int*)d_in[3];
  const float* Wt = (const float*)d_in[4];
  const float* bt = (const float*)d_in[5];
  const float* Wm = (const float*)d_in[6];
  const float* bm = (const float*)d_in[7];
  const float* Wh = (const float*)d_in[8];
  const float* bh = (const float*)d_in[9];
  float* out = (float*)d_out;
  char* ws = (char*)d_ws;

  char* wsA8   = ws + WS_A;
  unsigned short* wsAvid = (unsigned short*)(ws + WS_AVID);
  float* wsPsum = (float*)(ws + WS_PSUM);
  float* wsGold = (float*)(ws + WS_GOLD);
  float* wsTagl = (float*)(ws + WS_TAGL);
  char* wsWm8  = ws + WS_WM8;

  const bool useWm8 = ws_size >= WS_NEED;

  k_conv<<<9471, 256, 0, stream>>>(title, video, Wm, wsA8, wsAvid, wsWm8, wsTagl);
  if (useWm8)
    k_mlm<true><<<768, 256, 0, stream>>>(wsA8, Wm, wsWm8, bm, wsPsum);
  else
    k_mlm<false><<<768, 256, 0, stream>>>(wsA8, Wm, wsWm8, bm, wsPsum);
  k_tail<<<TAG_BLKS + GOLD_BLKS + EMB_BLKS, 256, 0, stream>>>(
      wsAvid, Wt, bt, ylab, title, lab, Wm, bm, video, Wh, bh,
      out, wsTagl, wsGold, out + OUT_EMB);
  k_final<<<1, 256, 0, stream>>>(wsPsum, wsGold, lab, wsTagl, out);
}

// Round 8
// 196.465 us; speedup vs baseline: 1.1537x; 1.1537x over previous
//
#include <hip/hip_runtime.h>
#include <hip/hip_bf16.h>
#include <math.h>

typedef short bf16x8 __attribute__((ext_vector_type(8)));
typedef float f32x4 __attribute__((ext_vector_type(4)));
typedef long i64x2 __attribute__((ext_vector_type(2)));

#define KDIM 768
#define NTAG 10000
#define NVOC 21128
#define HID 256
#define NTOK 4096
#define NCHUNK 24
#define CHUNK 881                 // ceil(21128/24)
#define NTILE 56                  // ceil(881/16)
#define M0 4.0f                   // fixed softmax shift (logits ~N(0,0.55))
#define WMSCALE 16.0f             // Wm pre-scale (fp8 subnormal avoidance)
#define INVSCALE 0.0625f

// ws layout (bytes)
#define WS_A     0ull                    // fp8  [4096][768] title          (3145728)
#define WS_AVID  3145728ull              // bf16 [32][768] video            (49152)
#define WS_PSUM  3194880ull              // f32  [4096][24]                 (393216)
#define WS_GOLD  3588096ull              // f32  [4096]                     (16384)
#define WS_TAGL  3604480ull              // f32  [1] atomic                 (64)
#define WS_WM8   3604544ull              // fp8  [21128][768] permuted,x16  (16226304)
#define WS_NEED  (WS_WM8 + 16226304ull + 65536ull)   // + OOB staging pad

#define OUT_EMB  320000
#define OUT_LTAG 328192
#define OUT_LMLM 328193

#define TAG_BLKS 313
#define GOLD_BLKS 1024
#define EMB_BLKS 32

typedef const __attribute__((address_space(1))) unsigned int glds_g;
typedef __attribute__((address_space(3))) unsigned int glds_l;

static __device__ __forceinline__ unsigned short f2bf(float f) {
  unsigned u = __builtin_bit_cast(unsigned, f);
  u = u + 0x7FFFu + ((u >> 16) & 1u);
  return (unsigned short)(u >> 16);
}

// pack 4 floats -> 4 fp8 e4m3 bytes
static __device__ __forceinline__ int pk4_fp8(float4 v, float scale) {
  int w = __builtin_amdgcn_cvt_pk_fp8_f32(v.x * scale, v.y * scale, 0, false);
  w = __builtin_amdgcn_cvt_pk_fp8_f32(v.z * scale, v.w * scale, w, true);
  return w;
}

// ---------------- conversions: title->fp8, video->bf16, Wm->fp8 permuted(x16) ----
// Wm8 permutation within each 64B k-block: out[g*16 + h*8 + b] = in[g*8 + h*32 + b]
// so a 16B granule (g) holds the B-slices for MFMA pair kk=2*kk2 (h=0) and +1 (h=1).
__global__ __launch_bounds__(256) void k_conv(
    const float* __restrict__ title, const float* __restrict__ video,
    const float* __restrict__ Wm,
    char* __restrict__ A8, unsigned short* __restrict__ Avid,
    char* __restrict__ Wm8, float* __restrict__ tagSum) {
  const int nT = 393216;            // title groups of 8 floats
  const int nV = 3072;              // video groups
  const int nW = 2028288;           // Wm groups
  int i = blockIdx.x * 256 + threadIdx.x;
  if (i == 0) tagSum[0] = 0.f;
  if (i < nT) {
    float4 v0 = ((const float4*)title)[i * 2];
    float4 v1 = ((const float4*)title)[i * 2 + 1];
    int2 o = {pk4_fp8(v0, 1.f), pk4_fp8(v1, 1.f)};
    *(int2*)(A8 + (size_t)i * 8) = o;
  } else if (i < nT + nV) {
    int j = i - nT;
    float4 v0 = ((const float4*)video)[j * 2];
    float4 v1 = ((const float4*)video)[j * 2 + 1];
    bf16x8 o;
    o[0] = (short)f2bf(v0.x); o[1] = (short)f2bf(v0.y);
    o[2] = (short)f2bf(v0.z); o[3] = (short)f2bf(v0.w);
    o[4] = (short)f2bf(v1.x); o[5] = (short)f2bf(v1.y);
    o[6] = (short)f2bf(v1.z); o[7] = (short)f2bf(v1.w);
    *(bf16x8*)(Avid + (size_t)j * 8) = o;
  } else {
    int j = i - nT - nV;
    if (j >= nW) return;
    float4 v0 = ((const float4*)Wm)[j * 2];
    float4 v1 = ((const float4*)Wm)[j * 2 + 1];
    int2 o = {pk4_fp8(v0, WMSCALE), pk4_fp8(v1, WMSCALE)};
    int row = j / 96;
    int koff = (j % 96) * 8;              // 0..760 step 8
    int kk2 = koff >> 6, w = koff & 63;
    int h = w >> 5, gg = (w & 31) >> 3;
    *(int2*)(Wm8 + (size_t)row * KDIM + kk2 * 64 + gg * 16 + h * 8) = o;
  }
}

// ---------------- MLM GEMM (fp8) + streaming sum-exp ----------------
// grid 768: chunk = bid%24 (XCD c%8), mt = bid/24. 4 waves x 32 rows.
// LDS B tile 12KB: byte = col*16 + g*256 + kk2*1024 (b128 reads, proven
// zero-conflict addressing from round 4). Granule = k-pair slices.
// 2-buffer, depth-1 prefetch, vmcnt(3), 2 barriers/tile (round-6 structure).
template<bool WM8>
__global__ __launch_bounds__(256)
__attribute__((amdgpu_waves_per_eu(3, 3)))
void k_mlm(
    const char* __restrict__ A8,
    const float* __restrict__ Wm,
    const char* __restrict__ Wm8,
    const float* __restrict__ bm,
    float* __restrict__ psum) {
  __shared__ __align__(1024) char Bsm[2][12288];              // 24 KiB dbuf (fp8)
  __shared__ float biasS[NTILE * 16];                         // 3.5 KiB
  const int tid = threadIdx.x;
  const int lane = tid & 63, g = lane >> 4, col = lane & 15;
  const int wave = tid >> 6;
  const int chunk = blockIdx.x % NCHUNK, mt = blockIdx.x / NCHUNK;
  const int nbeg = chunk * CHUNK;
  const int nend = min(nbeg + CHUNK, NVOC);

  // bias chunk -> LDS
  for (int i = tid; i < NTILE * 16; i += 256) {
    int n = nbeg + i;
    biasS[i] = (n < NVOC) ? bm[n] : 0.f;
  }

  // A fragments (full K in registers/AGPRs, fp8: 2 regs each)
  const int arow0 = mt * 128 + wave * 32;
  long a0[24], a1[24];
  #pragma unroll
  for (int kk = 0; kk < 24; ++kk) {
    a0[kk] = *(const long*)(A8 + (size_t)(arow0 + col) * KDIM + kk * 32 + g * 8);
    a1[kk] = *(const long*)(A8 + (size_t)(arow0 + 16 + col) * KDIM + kk * 32 + g * 8);
  }

  float s[8];
  #pragma unroll
  for (int i = 0; i < 8; ++i) s[i] = 0.f;

  // staging source offsets: granule sg = j*256+tid (16B):
  // row = sg&15, g' = (sg>>4)&3, kk2 = sg>>6 -> permuted source contiguous 16B
  int e[3];
  #pragma unroll
  for (int j = 0; j < 3; ++j) {
    int sg = j * 256 + tid;
    e[j] = (sg & 15) * KDIM + (sg >> 6) * 64 + ((sg >> 4) & 3) * 16;
  }

  const int off0 = col * 16 + g * 256;   // LDS read base; loop offset kk2*1024

  auto COMPUTE = [&](int t) {
    const char* B = &Bsm[t & 1][0] + off0;
    f32x4 acc0 = {0.f, 0.f, 0.f, 0.f}, acc1 = {0.f, 0.f, 0.f, 0.f};
    #pragma unroll
    for (int kk2 = 0; kk2 < 12; ++kk2) {
      i64x2 b = *(const i64x2*)(B + kk2 * 1024);
      acc0 = __builtin_amdgcn_mfma_f32_16x16x32_fp8_fp8(a0[2 * kk2], b[0], acc0, 0, 0, 0);
      acc1 = __builtin_amdgcn_mfma_f32_16x16x32_fp8_fp8(a1[2 * kk2], b[0], acc1, 0, 0, 0);
      acc0 = __builtin_amdgcn_mfma_f32_16x16x32_fp8_fp8(a0[2 * kk2 + 1], b[1], acc0, 0, 0, 0);
      acc1 = __builtin_amdgcn_mfma_f32_16x16x32_fp8_fp8(a1[2 * kk2 + 1], b[1], acc1, 0, 0, 0);
    }
    const int n0 = nbeg + t * 16;
    const bool valid = (n0 + col) < nend;
    const float bias = biasS[t * 16 + col];
    #pragma unroll
    for (int rr = 0; rr < 4; ++rr) {
      float x0 = acc0[rr] * INVSCALE + bias;
      float x1 = acc1[rr] * INVSCALE + bias;
      s[rr]     += valid ? __expf(x0 - M0) : 0.f;
      s[rr + 4] += valid ? __expf(x1 - M0) : 0.f;
    }
  };

  if constexpr (WM8) {
    auto STAGE = [&](int buf, int tt) {
      const char* src = Wm8 + (size_t)(nbeg + tt * 16) * KDIM;
      char* dst = &Bsm[buf][0] + wave * 1024;
      #pragma unroll
      for (int j = 0; j < 3; ++j) {
        __builtin_amdgcn_global_load_lds((glds_g*)(src + e[j]),
                                         (glds_l*)(dst + j * 4096), 16, 0, 0);
      }
    };
    STAGE(0, 0);
    asm volatile("s_waitcnt lgkmcnt(0)" ::: "memory");   // bias ds_writes done
    __builtin_amdgcn_s_barrier();
    for (int t = 0; t < NTILE; ++t) {
      int tn = (t + 1 < NTILE) ? t + 1 : 0;
      STAGE((t + 1) & 1, tn);                            // prefetch next tile
      asm volatile("s_waitcnt vmcnt(3)" ::: "memory");   // current tile staged
      __builtin_amdgcn_s_barrier();
      __builtin_amdgcn_sched_barrier(0);
      __builtin_amdgcn_s_setprio(1);
      COMPUTE(t);
      __builtin_amdgcn_s_setprio(0);
      __builtin_amdgcn_sched_barrier(0);
      __builtin_amdgcn_s_barrier();                      // all reads of cur done
    }
  } else {
    // fallback: serial staging from f32 Wm with inline fp8 cvt (x16), same layout
    __syncthreads();
    for (int t = 0; t < NTILE; ++t) {
      #pragma unroll
      for (int j = 0; j < 3; ++j) {
        int sg = j * 256 + tid;
        int n = nbeg + t * 16 + (sg & 15);
        int kk2 = sg >> 6, gg = (sg >> 4) & 3;
        int4 o = {0, 0, 0, 0};
        if (n < NVOC) {
          const float* wp = Wm + (size_t)n * KDIM + kk2 * 64 + gg * 8;
          float4 f0 = ((const float4*)wp)[0], f1 = ((const float4*)wp)[1];
          float4 f2 = ((const float4*)(wp + 32))[0], f3 = ((const float4*)(wp + 32))[1];
          o.x = pk4_fp8(f0, WMSCALE); o.y = pk4_fp8(f1, WMSCALE);
          o.z = pk4_fp8(f2, WMSCALE); o.w = pk4_fp8(f3, WMSCALE);
        }
        *(int4*)(&Bsm[0][0] + sg * 16) = o;
      }
      __syncthreads();
      COMPUTE(t);
      __syncthreads();
    }
  }

  // combine the 16 col-owner lanes per row, write per-chunk partial sums
  #pragma unroll
  for (int i = 0; i < 8; ++i) {
    float v = s[i];
    v += __shfl_xor(v, 1);
    v += __shfl_xor(v, 2);
    v += __shfl_xor(v, 4);
    v += __shfl_xor(v, 8);
    s[i] = v;
  }
  if (col == 0) {
    #pragma unroll
    for (int mblk = 0; mblk < 2; ++mblk)
      #pragma unroll
      for (int rr = 0; rr < 4; ++rr) {
        int tok = arow0 + mblk * 16 + g * 4 + rr;
        psum[tok * NCHUNK + chunk] = s[mblk * 4 + rr];
      }
  }
}

// ---------------- fused tail: tag (0..312) | gold (313..1336) | embed (1337..1368) ----
__global__ __launch_bounds__(256) void k_tail(
    const unsigned short* __restrict__ Avid,
    const float* __restrict__ Wt, const float* __restrict__ bt,
    const float* __restrict__ ylab,
    const float* __restrict__ title, const int* __restrict__ lab,
    const float* __restrict__ Wm, const float* __restrict__ bm,
    const float* __restrict__ video,
    const float* __restrict__ Wh, const float* __restrict__ bh,
    float* __restrict__ out_sig, float* __restrict__ tagSum,
    float* __restrict__ gold, float* __restrict__ out_emb) {
  __shared__ __align__(1024) char smem[49664];
  const int bid = blockIdx.x, tid = threadIdx.x;
  const int wave = tid >> 6, lane = tid & 63, g = lane >> 4, col = lane & 15;

  if (bid < TAG_BLKS) {
    // ---- tag head: 2 ntiles/block, Wt staged coalesced -> bf16 LDS ----
    unsigned short* Bt = (unsigned short*)smem;       // [2][24 KiB]
    float* wsum = (float*)(smem + 49152);
    #pragma unroll
    for (int j = 0; j < 12; ++j) {
      int sg = j * 256 + tid;
      int tt = (j >= 6) ? 1 : 0;
      int sgl = sg - tt * 1536;
      int kk = sgl >> 6, c = (sgl & 63) >> 2, gg = sgl & 3;
      int n = (bid * 2 + tt) * 16 + c;
      bf16x8 o = {};
      if (n < NTAG) {
        const float* wp = Wt + (size_t)n * KDIM + kk * 32 + gg * 8;
        float4 f0 = ((const float4*)wp)[0], f1 = ((const float4*)wp)[1];
        o[0] = (short)f2bf(f0.x); o[1] = (short)f2bf(f0.y);
        o[2] = (short)f2bf(f0.z); o[3] = (short)f2bf(f0.w);
        o[4] = (short)f2bf(f1.x); o[5] = (short)f2bf(f1.y);
        o[6] = (short)f2bf(f1.z); o[7] = (short)f2bf(f1.w);
      }
      *(bf16x8*)((char*)Bt + sg * 16) = o;
    }
    __syncthreads();

    const int ntile = bid * 2 + (wave >> 1), mhalf = wave & 1;
    float lacc = 0.f;
    if (ntile < 625) {
      bf16x8 a[24];
      #pragma unroll
      for (int kk = 0; kk < 24; ++kk)
        a[kk] = *(const bf16x8*)(Avid + (size_t)(mhalf * 16 + col) * KDIM + kk * 32 + g * 8);
      const char* Bb = (const char*)Bt + (wave >> 1) * 24576 + col * 64 + g * 16;
      f32x4 acc = {0.f, 0.f, 0.f, 0.f};
      #pragma unroll
      for (int kk = 0; kk < 24; ++kk) {
        bf16x8 b = *(const bf16x8*)(Bb + kk * 1024);
        acc = __builtin_amdgcn_mfma_f32_16x16x32_bf16(a[kk], b, acc, 0, 0, 0);
      }
      const int nc = ntile * 16 + col;
      if (nc < NTAG) {
        const float bias = bt[nc];
        #pragma unroll
        for (int rr = 0; rr < 4; ++rr) {
          int brow = mhalf * 16 + g * 4 + rr;
          float x = acc[rr] + bias;
          out_sig[(size_t)brow * NTAG + nc] = 1.f / (1.f + __expf(-x));
          float y = ylab[(size_t)brow * NTAG + nc];
          lacc += fmaxf(x, 0.f) - x * y + log1pf(__expf(-fabsf(x)));
        }
      }
    }
    #pragma unroll
    for (int m = 32; m; m >>= 1) lacc += __shfl_xor(lacc, m);
    if (lane == 0) wsum[wave] = lacc;
    __syncthreads();
    if (tid == 0) atomicAdd(tagSum, wsum[0] + wsum[1] + wsum[2] + wsum[3]);

  } else if (bid < TAG_BLKS + GOLD_BLKS) {
    // ---- gold logit per token (f32 exact) ----
    int tok = (bid - TAG_BLKS) * 4 + wave;
    int l = lab[tok];
    float acc = 0.f;
    #pragma unroll
    for (int j = 0; j < 12; ++j) {
      int k = j * 64 + lane;
      acc += title[(size_t)tok * KDIM + k] * Wm[(size_t)l * KDIM + k];
    }
    #pragma unroll
    for (int m = 32; m; m >>= 1) acc += __shfl_xor(acc, m);
    if (lane == 0) gold[tok] = acc + bm[l];

  } else {
    // ---- embedding head (f32 exact) ----
    float* feat = (float*)smem;
    float* red = (float*)(smem + 49152);
    const int b = bid - TAG_BLKS - GOLD_BLKS;
    #pragma unroll
    for (int j = 0; j < 6; ++j) {
      int k = j * 256 + tid;
      feat[k] = (k < KDIM) ? video[(size_t)b * KDIM + k]
                           : title[(size_t)b * 128 * KDIM + (k - KDIM)];
    }
    __syncthreads();
    float acc = bh[tid];
    #pragma unroll 8
    for (int k = 0; k < 1536; k += 4) {
      float4 w = *(const float4*)(Wh + (size_t)tid * 1536 + k);
      acc += w.x * feat[k] + w.y * feat[k + 1] + w.z * feat[k + 2] + w.w * feat[k + 3];
    }
    float ss = acc * acc;
    #pragma unroll
    for (int m = 32; m; m >>= 1) ss += __shfl_xor(ss, m);
    if (lane == 0) red[wave] = ss;
    __syncthreads();
    float nrm = sqrtf(red[0] + red[1] + red[2] + red[3]);
    float scale = 1.f / fmaxf(nrm, 1e-12f);
    out_emb[(size_t)b * HID + tid] = acc * scale;
  }
}

// ---------------- finalize losses ----------------
__global__ __launch_bounds__(256) void k_final(
    const float* __restrict__ psum, const float* __restrict__ gold,
    const int* __restrict__ lab, const float* __restrict__ tagSum,
    float* __restrict__ out) {
  __shared__ float red[4];
  const int tid = threadIdx.x, wave = tid >> 6, lane = tid & 63;
  if (tid == 0) out[OUT_LTAG] = tagSum[0] / 320000.f;

  float lm = 0.f;
  for (int tok = tid; tok < NTOK; tok += 256) {
    float S = 0.f;
    #pragma unroll
    for (int c = 0; c < NCHUNK; ++c) S += psum[tok * NCHUNK + c];
    float lse = M0 + logf(S);
    if (lab[tok] != 0) lm += lse - gold[tok];
  }
  #pragma unroll
  for (int m = 32; m; m >>= 1) lm += __shfl_xor(lm, m);
  if (lane == 0) red[wave] = lm;
  __syncthreads();
  if (tid == 0) out[OUT_LMLM] = red[0] + red[1] + red[2] + red[3];
}

extern "C" void kernel_launch(void* const* d_in, const int* in_sizes, int n_in,
                              void* d_out, int out_size, void* d_ws, size_t ws_size,
                              hipStream_t stream) {
  const float* video = (const float*)d_in[0];
  const float* title = (const float*)d_in[1];
  const float* ylab  = (const float*)d_in[2];
  const int*   lab   = (const int*)d_in[3];
  const float* Wt = (const float*)d_in[4];
  const float* bt = (const float*)d_in[5];
  const float* Wm = (const float*)d_in[6];
  const float* bm = (const float*)d_in[7];
  const float* Wh = (const float*)d_in[8];
  const float* bh = (const float*)d_in[9];
  float* out = (float*)d_out;
  char* ws = (char*)d_ws;

  char* wsA8   = ws + WS_A;
  unsigned short* wsAvid = (unsigned short*)(ws + WS_AVID);
  float* wsPsum = (float*)(ws + WS_PSUM);
  float* wsGold = (float*)(ws + WS_GOLD);
  float* wsTagl = (float*)(ws + WS_TAGL);
  char* wsWm8  = ws + WS_WM8;

  const bool useWm8 = ws_size >= WS_NEED;

  k_conv<<<9471, 256, 0, stream>>>(title, video, Wm, wsA8, wsAvid, wsWm8, wsTagl);
  if (useWm8)
    k_mlm<true><<<768, 256, 0, stream>>>(wsA8, Wm, wsWm8, bm, wsPsum);
  else
    k_mlm<false><<<768, 256, 0, stream>>>(wsA8, Wm, wsWm8, bm, wsPsum);
  k_tail<<<TAG_BLKS + GOLD_BLKS + EMB_BLKS, 256, 0, stream>>>(
      wsAvid, Wt, bt, ylab, title, lab, Wm, bm, video, Wh, bh,
      out, wsTagl, wsGold, out + OUT_EMB);
  k_final<<<1, 256, 0, stream>>>(wsPsum, wsGold, lab, wsTagl, out);
}

// Round 9
// 196.124 us; speedup vs baseline: 1.1557x; 1.0017x over previous
//
#include <hip/hip_runtime.h>
#include <hip/hip_bf16.h>
#include <math.h>

typedef short bf16x8 __attribute__((ext_vector_type(8)));
typedef float f32x4 __attribute__((ext_vector_type(4)));
typedef long i64x2 __attribute__((ext_vector_type(2)));

#define KDIM 768
#define NTAG 10000
#define NVOC 21128
#define HID 256
#define NTOK 4096
#define NCHUNK 24
#define CHUNK 881                 // ceil(21128/24)
#define NTILE 56                  // ceil(881/16)
#define M0 4.0f                   // fixed softmax shift (logits ~N(0,0.55))
#define WMSCALE 16.0f             // Wm pre-scale (fp8 subnormal avoidance)
#define INVSCALE 0.0625f
#define LOG2E 1.44269504f

// ws layout (bytes)
#define WS_A     0ull                    // fp8  [4096][768] title          (3145728)
#define WS_AVID  3145728ull              // bf16 [32][768] video            (49152)
#define WS_PSUM  3194880ull              // f32  [4096][24]                 (393216)
#define WS_GOLD  3588096ull              // f32  [4096]                     (16384)
#define WS_TAGL  3604480ull              // f32  [1] atomic                 (64)
#define WS_WM8   3604544ull              // fp8  [21128][768] permuted,x16  (16226304)
#define WS_NEED  (WS_WM8 + 16226304ull + 65536ull)   // + OOB staging pad

#define OUT_EMB  320000
#define OUT_LTAG 328192
#define OUT_LMLM 328193

#define TAG_BLKS 313
#define GOLD_BLKS 1024
#define EMB_BLKS 32

typedef const __attribute__((address_space(1))) unsigned int glds_g;
typedef __attribute__((address_space(3))) unsigned int glds_l;

static __device__ __forceinline__ unsigned short f2bf(float f) {
  unsigned u = __builtin_bit_cast(unsigned, f);
  u = u + 0x7FFFu + ((u >> 16) & 1u);
  return (unsigned short)(u >> 16);
}

// pack 4 floats -> 4 fp8 e4m3 bytes
static __device__ __forceinline__ int pk4_fp8(float4 v, float scale) {
  int w = __builtin_amdgcn_cvt_pk_fp8_f32(v.x * scale, v.y * scale, 0, false);
  w = __builtin_amdgcn_cvt_pk_fp8_f32(v.z * scale, v.w * scale, w, true);
  return w;
}

// ---------------- conversions: title->fp8, video->bf16, Wm->fp8 permuted(x16) ----
// Wm8 permutation within each 64B k-block: out[g*16 + h*8 + b] = in[g*8 + h*32 + b]
// so a 16B granule (g) holds the B-slices for MFMA pair kk=2*kk2 (h=0) and +1 (h=1).
__global__ __launch_bounds__(256) void k_conv(
    const float* __restrict__ title, const float* __restrict__ video,
    const float* __restrict__ Wm,
    char* __restrict__ A8, unsigned short* __restrict__ Avid,
    char* __restrict__ Wm8, float* __restrict__ tagSum) {
  const int nT = 393216;            // title groups of 8 floats
  const int nV = 3072;              // video groups
  const int nW = 2028288;           // Wm groups
  int i = blockIdx.x * 256 + threadIdx.x;
  if (i == 0) tagSum[0] = 0.f;
  if (i < nT) {
    float4 v0 = ((const float4*)title)[i * 2];
    float4 v1 = ((const float4*)title)[i * 2 + 1];
    int2 o = {pk4_fp8(v0, 1.f), pk4_fp8(v1, 1.f)};
    *(int2*)(A8 + (size_t)i * 8) = o;
  } else if (i < nT + nV) {
    int j = i - nT;
    float4 v0 = ((const float4*)video)[j * 2];
    float4 v1 = ((const float4*)video)[j * 2 + 1];
    bf16x8 o;
    o[0] = (short)f2bf(v0.x); o[1] = (short)f2bf(v0.y);
    o[2] = (short)f2bf(v0.z); o[3] = (short)f2bf(v0.w);
    o[4] = (short)f2bf(v1.x); o[5] = (short)f2bf(v1.y);
    o[6] = (short)f2bf(v1.z); o[7] = (short)f2bf(v1.w);
    *(bf16x8*)(Avid + (size_t)j * 8) = o;
  } else {
    int j = i - nT - nV;
    if (j >= nW) return;
    float4 v0 = ((const float4*)Wm)[j * 2];
    float4 v1 = ((const float4*)Wm)[j * 2 + 1];
    int2 o = {pk4_fp8(v0, WMSCALE), pk4_fp8(v1, WMSCALE)};
    int row = j / 96;
    int koff = (j % 96) * 8;              // 0..760 step 8
    int kk2 = koff >> 6, w = koff & 63;
    int h = w >> 5, gg = (w & 31) >> 3;
    *(int2*)(Wm8 + (size_t)row * KDIM + kk2 * 64 + gg * 16 + h * 8) = o;
  }
}

// ---------------- MLM GEMM (fp8) + streaming sum-exp ----------------
// grid 768: chunk = bid%24 (XCD c%8), mt = bid/24. 4 waves x 32 rows.
// LDS B tile 12KB: byte = col*16 + g*256 + kk2*1024 (b128, zero-conflict).
// QUAD-buffer, depth-3 prefetch, ONE barrier/tile, counted vmcnt(6).
// Epilogue: bias2 = (bm - M0)*log2e (or -1e30 invalid) -> fma+exp2+add only.
template<bool WM8>
__global__ __launch_bounds__(256)
__attribute__((amdgpu_waves_per_eu(3, 3)))
void k_mlm(
    const char* __restrict__ A8,
    const float* __restrict__ Wm,
    const char* __restrict__ Wm8,
    const float* __restrict__ bm,
    float* __restrict__ psum) {
  __shared__ __align__(1024) char Bsm[4][12288];              // 48 KiB quad (fp8)
  __shared__ float biasS[NTILE * 16];                         // 3.5 KiB
  const int tid = threadIdx.x;
  const int lane = tid & 63, g = lane >> 4, col = lane & 15;
  const int wave = tid >> 6;
  const int chunk = blockIdx.x % NCHUNK, mt = blockIdx.x / NCHUNK;
  const int nbeg = chunk * CHUNK;
  const int nend = min(nbeg + CHUNK, NVOC);

  // bias chunk -> LDS, with -M0 and log2e folded; invalid cols -> -1e30
  for (int i = tid; i < NTILE * 16; i += 256) {
    int n = nbeg + i;
    biasS[i] = (n < nend) ? (bm[n] - M0) * LOG2E : -1e30f;
  }

  // A fragments (full K in registers/AGPRs, fp8: 2 regs each)
  const int arow0 = mt * 128 + wave * 32;
  long a0[24], a1[24];
  #pragma unroll
  for (int kk = 0; kk < 24; ++kk) {
    a0[kk] = *(const long*)(A8 + (size_t)(arow0 + col) * KDIM + kk * 32 + g * 8);
    a1[kk] = *(const long*)(A8 + (size_t)(arow0 + 16 + col) * KDIM + kk * 32 + g * 8);
  }

  float s[8];
  #pragma unroll
  for (int i = 0; i < 8; ++i) s[i] = 0.f;

  // staging source offsets: granule sg = j*256+tid (16B):
  // row = sg&15, g' = (sg>>4)&3, kk2 = sg>>6 -> permuted source contiguous 16B
  int e[3];
  #pragma unroll
  for (int j = 0; j < 3; ++j) {
    int sg = j * 256 + tid;
    e[j] = (sg & 15) * KDIM + (sg >> 6) * 64 + ((sg >> 4) & 3) * 16;
  }

  const int off0 = col * 16 + g * 256;   // LDS read base; loop offset kk2*1024
  const float kinv = INVSCALE * LOG2E;

  auto COMPUTE = [&](int t) {
    const char* B = &Bsm[t & 3][0] + off0;
    f32x4 acc0 = {0.f, 0.f, 0.f, 0.f}, acc1 = {0.f, 0.f, 0.f, 0.f};
    #pragma unroll
    for (int kk2 = 0; kk2 < 12; ++kk2) {
      i64x2 b = *(const i64x2*)(B + kk2 * 1024);
      acc0 = __builtin_amdgcn_mfma_f32_16x16x32_fp8_fp8(a0[2 * kk2], b[0], acc0, 0, 0, 0);
      acc1 = __builtin_amdgcn_mfma_f32_16x16x32_fp8_fp8(a1[2 * kk2], b[0], acc1, 0, 0, 0);
      acc0 = __builtin_amdgcn_mfma_f32_16x16x32_fp8_fp8(a0[2 * kk2 + 1], b[1], acc0, 0, 0, 0);
      acc1 = __builtin_amdgcn_mfma_f32_16x16x32_fp8_fp8(a1[2 * kk2 + 1], b[1], acc1, 0, 0, 0);
    }
    const float bias2 = biasS[t * 16 + col];
    #pragma unroll
    for (int rr = 0; rr < 4; ++rr) {
      s[rr]     += exp2f(fmaf(acc0[rr], kinv, bias2));
      s[rr + 4] += exp2f(fmaf(acc1[rr], kinv, bias2));
    }
  };

  if constexpr (WM8) {
    auto STAGE = [&](int buf, int tt) {
      const char* src = Wm8 + (size_t)(nbeg + tt * 16) * KDIM;
      char* dst = &Bsm[buf][0] + wave * 1024;
      #pragma unroll
      for (int j = 0; j < 3; ++j) {
        __builtin_amdgcn_global_load_lds((glds_g*)(src + e[j]),
                                         (glds_l*)(dst + j * 4096), 16, 0, 0);
      }
    };
    STAGE(0, 0); STAGE(1, 1); STAGE(2, 2);               // depth-3 prologue
    asm volatile("s_waitcnt lgkmcnt(0)" ::: "memory");   // bias ds_writes done
    for (int t = 0; t < NTILE; ++t) {
      asm volatile("s_waitcnt vmcnt(6)" ::: "memory");   // tile t staged (own 3)
      __builtin_amdgcn_s_barrier();                      // all waves: t ready AND
      __builtin_amdgcn_sched_barrier(0);                 //  t-1 reads complete
      int tp = t + 3;
      STAGE((t + 3) & 3, (tp < NTILE) ? tp : 0);         // prefetch t+3
      __builtin_amdgcn_s_setprio(1);
      COMPUTE(t);
      __builtin_amdgcn_s_setprio(0);
      __builtin_amdgcn_sched_barrier(0);
    }
  } else {
    // fallback: serial staging from f32 Wm with inline fp8 cvt (x16), same layout
    __syncthreads();
    for (int t = 0; t < NTILE; ++t) {
      #pragma unroll
      for (int j = 0; j < 3; ++j) {
        int sg = j * 256 + tid;
        int n = nbeg + t * 16 + (sg & 15);
        int kk2 = sg >> 6, gg = (sg >> 4) & 3;
        int4 o = {0, 0, 0, 0};
        if (n < NVOC) {
          const float* wp = Wm + (size_t)n * KDIM + kk2 * 64 + gg * 8;
          float4 f0 = ((const float4*)wp)[0], f1 = ((const float4*)wp)[1];
          float4 f2 = ((const float4*)(wp + 32))[0], f3 = ((const float4*)(wp + 32))[1];
          o.x = pk4_fp8(f0, WMSCALE); o.y = pk4_fp8(f1, WMSCALE);
          o.z = pk4_fp8(f2, WMSCALE); o.w = pk4_fp8(f3, WMSCALE);
        }
        *(int4*)(&Bsm[0][0] + sg * 16) = o;
      }
      __syncthreads();
      COMPUTE(t);
      __syncthreads();
    }
  }

  // combine the 16 col-owner lanes per row, write per-chunk partial sums
  #pragma unroll
  for (int i = 0; i < 8; ++i) {
    float v = s[i];
    v += __shfl_xor(v, 1);
    v += __shfl_xor(v, 2);
    v += __shfl_xor(v, 4);
    v += __shfl_xor(v, 8);
    s[i] = v;
  }
  if (col == 0) {
    #pragma unroll
    for (int mblk = 0; mblk < 2; ++mblk)
      #pragma unroll
      for (int rr = 0; rr < 4; ++rr) {
        int tok = arow0 + mblk * 16 + g * 4 + rr;
        psum[tok * NCHUNK + chunk] = s[mblk * 4 + rr];
      }
  }
}

// ---------------- fused tail: tag (0..312) | gold (313..1336) | embed (1337..1368) ----
__global__ __launch_bounds__(256) void k_tail(
    const unsigned short* __restrict__ Avid,
    const float* __restrict__ Wt, const float* __restrict__ bt,
    const float* __restrict__ ylab,
    const float* __restrict__ title, const int* __restrict__ lab,
    const float* __restrict__ Wm, const float* __restrict__ bm,
    const float* __restrict__ video,
    const float* __restrict__ Wh, const float* __restrict__ bh,
    float* __restrict__ out_sig, float* __restrict__ tagSum,
    float* __restrict__ gold, float* __restrict__ out_emb) {
  __shared__ __align__(1024) char smem[49664];
  const int bid = blockIdx.x, tid = threadIdx.x;
  const int wave = tid >> 6, lane = tid & 63, g = lane >> 4, col = lane & 15;

  if (bid < TAG_BLKS) {
    // ---- tag head: 2 ntiles/block, Wt staged coalesced -> bf16 LDS ----
    unsigned short* Bt = (unsigned short*)smem;       // [2][24 KiB]
    float* wsum = (float*)(smem + 49152);
    #pragma unroll
    for (int j = 0; j < 12; ++j) {
      int sg = j * 256 + tid;
      int tt = (j >= 6) ? 1 : 0;
      int sgl = sg - tt * 1536;
      int kk = sgl >> 6, c = (sgl & 63) >> 2, gg = sgl & 3;
      int n = (bid * 2 + tt) * 16 + c;
      bf16x8 o = {};
      if (n < NTAG) {
        const float* wp = Wt + (size_t)n * KDIM + kk * 32 + gg * 8;
        float4 f0 = ((const float4*)wp)[0], f1 = ((const float4*)wp)[1];
        o[0] = (short)f2bf(f0.x); o[1] = (short)f2bf(f0.y);
        o[2] = (short)f2bf(f0.z); o[3] = (short)f2bf(f0.w);
        o[4] = (short)f2bf(f1.x); o[5] = (short)f2bf(f1.y);
        o[6] = (short)f2bf(f1.z); o[7] = (short)f2bf(f1.w);
      }
      *(bf16x8*)((char*)Bt + sg * 16) = o;
    }
    __syncthreads();

    const int ntile = bid * 2 + (wave >> 1), mhalf = wave & 1;
    float lacc = 0.f;
    if (ntile < 625) {
      bf16x8 a[24];
      #pragma unroll
      for (int kk = 0; kk < 24; ++kk)
        a[kk] = *(const bf16x8*)(Avid + (size_t)(mhalf * 16 + col) * KDIM + kk * 32 + g * 8);
      const char* Bb = (const char*)Bt + (wave >> 1) * 24576 + col * 64 + g * 16;
      f32x4 acc = {0.f, 0.f, 0.f, 0.f};
      #pragma unroll
      for (int kk = 0; kk < 24; ++kk) {
        bf16x8 b = *(const bf16x8*)(Bb + kk * 1024);
        acc = __builtin_amdgcn_mfma_f32_16x16x32_bf16(a[kk], b, acc, 0, 0, 0);
      }
      const int nc = ntile * 16 + col;
      if (nc < NTAG) {
        const float bias = bt[nc];
        #pragma unroll
        for (int rr = 0; rr < 4; ++rr) {
          int brow = mhalf * 16 + g * 4 + rr;
          float x = acc[rr] + bias;
          out_sig[(size_t)brow * NTAG + nc] = 1.f / (1.f + __expf(-x));
          float y = ylab[(size_t)brow * NTAG + nc];
          lacc += fmaxf(x, 0.f) - x * y + log1pf(__expf(-fabsf(x)));
        }
      }
    }
    #pragma unroll
    for (int m = 32; m; m >>= 1) lacc += __shfl_xor(lacc, m);
    if (lane == 0) wsum[wave] = lacc;
    __syncthreads();
    if (tid == 0) atomicAdd(tagSum, wsum[0] + wsum[1] + wsum[2] + wsum[3]);

  } else if (bid < TAG_BLKS + GOLD_BLKS) {
    // ---- gold logit per token (f32 exact) ----
    int tok = (bid - TAG_BLKS) * 4 + wave;
    int l = lab[tok];
    float acc = 0.f;
    #pragma unroll
    for (int j = 0; j < 12; ++j) {
      int k = j * 64 + lane;
      acc += title[(size_t)tok * KDIM + k] * Wm[(size_t)l * KDIM + k];
    }
    #pragma unroll
    for (int m = 32; m; m >>= 1) acc += __shfl_xor(acc, m);
    if (lane == 0) gold[tok] = acc + bm[l];

  } else {
    // ---- embedding head (f32 exact) ----
    float* feat = (float*)smem;
    float* red = (float*)(smem + 49152);
    const int b = bid - TAG_BLKS - GOLD_BLKS;
    #pragma unroll
    for (int j = 0; j < 6; ++j) {
      int k = j * 256 + tid;
      feat[k] = (k < KDIM) ? video[(size_t)b * KDIM + k]
                           : title[(size_t)b * 128 * KDIM + (k - KDIM)];
    }
    __syncthreads();
    float acc = bh[tid];
    #pragma unroll 8
    for (int k = 0; k < 1536; k += 4) {
      float4 w = *(const float4*)(Wh + (size_t)tid * 1536 + k);
      acc += w.x * feat[k] + w.y * feat[k + 1] + w.z * feat[k + 2] + w.w * feat[k + 3];
    }
    float ss = acc * acc;
    #pragma unroll
    for (int m = 32; m; m >>= 1) ss += __shfl_xor(ss, m);
    if (lane == 0) red[wave] = ss;
    __syncthreads();
    float nrm = sqrtf(red[0] + red[1] + red[2] + red[3]);
    float scale = 1.f / fmaxf(nrm, 1e-12f);
    out_emb[(size_t)b * HID + tid] = acc * scale;
  }
}

// ---------------- finalize losses ----------------
__global__ __launch_bounds__(256) void k_final(
    const float* __restrict__ psum, const float* __restrict__ gold,
    const int* __restrict__ lab, const float* __restrict__ tagSum,
    float* __restrict__ out) {
  __shared__ float red[4];
  const int tid = threadIdx.x, wave = tid >> 6, lane = tid & 63;
  if (tid == 0) out[OUT_LTAG] = tagSum[0] / 320000.f;

  float lm = 0.f;
  for (int tok = tid; tok < NTOK; tok += 256) {
    float S = 0.f;
    #pragma unroll
    for (int c = 0; c < NCHUNK; ++c) S += psum[tok * NCHUNK + c];
    float lse = M0 + logf(S);
    if (lab[tok] != 0) lm += lse - gold[tok];
  }
  #pragma unroll
  for (int m = 32; m; m >>= 1) lm += __shfl_xor(lm, m);
  if (lane == 0) red[wave] = lm;
  __syncthreads();
  if (tid == 0) out[OUT_LMLM] = red[0] + red[1] + red[2] + red[3];
}

extern "C" void kernel_launch(void* const* d_in, const int* in_sizes, int n_in,
                              void* d_out, int out_size, void* d_ws, size_t ws_size,
                              hipStream_t stream) {
  const float* video = (const float*)d_in[0];
  const float* title = (const float*)d_in[1];
  const float* ylab  = (const float*)d_in[2];
  const int*   lab   = (const int*)d_in[3];
  const float* Wt = (const float*)d_in[4];
  const float* bt = (const float*)d_in[5];
  const float* Wm = (const float*)d_in[6];
  const float* bm = (const float*)d_in[7];
  const float* Wh = (const float*)d_in[8];
  const float* bh = (const float*)d_in[9];
  float* out = (float*)d_out;
  char* ws = (char*)d_ws;

  char* wsA8   = ws + WS_A;
  unsigned short* wsAvid = (unsigned short*)(ws + WS_AVID);
  float* wsPsum = (float*)(ws + WS_PSUM);
  float* wsGold = (float*)(ws + WS_GOLD);
  float* wsTagl = (float*)(ws + WS_TAGL);
  char* wsWm8  = ws + WS_WM8;

  const bool useWm8 = ws_size >= WS_NEED;

  k_conv<<<9471, 256, 0, stream>>>(title, video, Wm, wsA8, wsAvid, wsWm8, wsTagl);
  if (useWm8)
    k_mlm<true><<<768, 256, 0, stream>>>(wsA8, Wm, wsWm8, bm, wsPsum);
  else
    k_mlm<false><<<768, 256, 0, stream>>>(wsA8, Wm, wsWm8, bm, wsPsum);
  k_tail<<<TAG_BLKS + GOLD_BLKS + EMB_BLKS, 256, 0, stream>>>(
      wsAvid, Wt, bt, ylab, title, lab, Wm, bm, video, Wh, bh,
      out, wsTagl, wsGold, out + OUT_EMB);
  k_final<<<1, 256, 0, stream>>>(wsPsum, wsGold, lab, wsTagl, out);
}

// Round 10
// 188.087 us; speedup vs baseline: 1.2051x; 1.0427x over previous
//
#include <hip/hip_runtime.h>
#include <hip/hip_bf16.h>
#include <math.h>

typedef short bf16x8 __attribute__((ext_vector_type(8)));
typedef float f32x4 __attribute__((ext_vector_type(4)));

#define KDIM 768
#define NTAG 10000
#define NVOC 21128
#define HID 256
#define NTOK 4096
#define NCHUNK 24
#define CHUNK 881                 // ceil(21128/24)
#define NTILE 56                  // ceil(881/16)
#define M0 4.0f                   // fixed softmax shift (logits ~N(0,0.55))
#define WMSCALE 16.0f             // Wm pre-scale (fp8 subnormal avoidance)
#define INVSCALE 0.0625f
#define LOG2E 1.44269504f

// ws layout (bytes)
#define WS_A     0ull                    // fp8  [4096][768] title          (3145728)
#define WS_AVID  3145728ull              // bf16 [32][768] video            (49152)
#define WS_PSUM  3194880ull              // f32  [4096][24]                 (393216)
#define WS_GOLD  3588096ull              // f32  [4096]                     (16384)
#define WS_TAGL  3604480ull              // f32  [1] atomic                 (64)
#define WS_WM8   3604544ull              // fp8  [21128][768] row-major,x16 (16226304)
#define WS_NEED  (WS_WM8 + 16226304ull + 65536ull)   // + OOB staging pad

#define OUT_EMB  320000
#define OUT_LTAG 328192
#define OUT_LMLM 328193

#define TAG_BLKS 313
#define GOLD_BLKS 1024
#define EMB_BLKS 32

typedef const __attribute__((address_space(1))) unsigned int glds_g;
typedef __attribute__((address_space(3))) unsigned int glds_l;

static __device__ __forceinline__ unsigned short f2bf(float f) {
  unsigned u = __builtin_bit_cast(unsigned, f);
  u = u + 0x7FFFu + ((u >> 16) & 1u);
  return (unsigned short)(u >> 16);
}

// pack 4 floats -> 4 fp8 e4m3 bytes
static __device__ __forceinline__ int pk4_fp8(float4 v, float scale) {
  int w = __builtin_amdgcn_cvt_pk_fp8_f32(v.x * scale, v.y * scale, 0, false);
  w = __builtin_amdgcn_cvt_pk_fp8_f32(v.z * scale, v.w * scale, w, true);
  return w;
}

// ---------------- conversions: title->fp8, video->bf16, Wm->fp8 row-major(x16) ----
__global__ __launch_bounds__(256) void k_conv(
    const float* __restrict__ title, const float* __restrict__ video,
    const float* __restrict__ Wm,
    char* __restrict__ A8, unsigned short* __restrict__ Avid,
    char* __restrict__ Wm8, float* __restrict__ tagSum) {
  const int nT = 393216;            // title groups of 8 floats
  const int nV = 3072;              // video groups
  const int nW = 2028288;           // Wm groups
  int i = blockIdx.x * 256 + threadIdx.x;
  if (i == 0) tagSum[0] = 0.f;
  if (i < nT) {
    float4 v0 = ((const float4*)title)[i * 2];
    float4 v1 = ((const float4*)title)[i * 2 + 1];
    int2 o = {pk4_fp8(v0, 1.f), pk4_fp8(v1, 1.f)};
    *(int2*)(A8 + (size_t)i * 8) = o;
  } else if (i < nT + nV) {
    int j = i - nT;
    float4 v0 = ((const float4*)video)[j * 2];
    float4 v1 = ((const float4*)video)[j * 2 + 1];
    bf16x8 o;
    o[0] = (short)f2bf(v0.x); o[1] = (short)f2bf(v0.y);
    o[2] = (short)f2bf(v0.z); o[3] = (short)f2bf(v0.w);
    o[4] = (short)f2bf(v1.x); o[5] = (short)f2bf(v1.y);
    o[6] = (short)f2bf(v1.z); o[7] = (short)f2bf(v1.w);
    *(bf16x8*)(Avid + (size_t)j * 8) = o;
  } else {
    int j = i - nT - nV;
    if (j >= nW) return;
    float4 v0 = ((const float4*)Wm)[j * 2];
    float4 v1 = ((const float4*)Wm)[j * 2 + 1];
    int2 o = {pk4_fp8(v0, WMSCALE), pk4_fp8(v1, WMSCALE)};
    *(int2*)(Wm8 + (size_t)j * 8) = o;
  }
}

// ---------------- MLM GEMM (fp8) + streaming sum-exp ----------------
// EXACT round-6 structure (measured best: 111.6us, MfmaUtil 51.6):
// grid 768: chunk = bid%24 (XCD c%8), mt = bid/24. 4 waves x 32 rows.
// LDS B tile 12KB: byte = kk2*1024 + col*64 + ((kk&1)*32+g*8)^(((col>>1)&3)<<4)
// b64 reads (24/tile/wave, short dep chains); 16B swizzle granule keeps
// global_load_lds source contiguous. 2-buffer, vmcnt(3), 2 barriers, setprio.
// Epilogue (r9 slimming): bias2=(bm-M0)*log2e or -1e30 -> fma+exp2+add only.
template<bool WM8>
__global__ __launch_bounds__(256)
__attribute__((amdgpu_waves_per_eu(3, 3)))
void k_mlm(
    const char* __restrict__ A8,
    const float* __restrict__ Wm,
    const char* __restrict__ Wm8,
    const float* __restrict__ bm,
    float* __restrict__ psum) {
  __shared__ __align__(1024) char Bsm[2][12288];              // 24 KiB dbuf (fp8)
  __shared__ float biasS[NTILE * 16];                         // 3.5 KiB
  const int tid = threadIdx.x;
  const int lane = tid & 63, g = lane >> 4, col = lane & 15;
  const int wave = tid >> 6;
  const int chunk = blockIdx.x % NCHUNK, mt = blockIdx.x / NCHUNK;
  const int nbeg = chunk * CHUNK;
  const int nend = min(nbeg + CHUNK, NVOC);

  // bias chunk -> LDS, -M0 and log2e folded; invalid cols -> -1e30
  for (int i = tid; i < NTILE * 16; i += 256) {
    int n = nbeg + i;
    biasS[i] = (n < nend) ? (bm[n] - M0) * LOG2E : -1e30f;
  }

  // A fragments (full K in registers/AGPRs, fp8: 2 regs each)
  const int arow0 = mt * 128 + wave * 32;
  long a0[24], a1[24];
  #pragma unroll
  for (int kk = 0; kk < 24; ++kk) {
    a0[kk] = *(const long*)(A8 + (size_t)(arow0 + col) * KDIM + kk * 32 + g * 8);
    a1[kk] = *(const long*)(A8 + (size_t)(arow0 + 16 + col) * KDIM + kk * 32 + g * 8);
  }

  float s[8];
  #pragma unroll
  for (int i = 0; i < 8; ++i) s[i] = 0.f;

  // staging source offsets (r6): granule sg = j*256+tid (16B):
  // kk2=sg/64, nl=(sg>>2)&15, q=sg&3, q'=q^((nl>>1)&3)
  int e[3];
  #pragma unroll
  for (int j = 0; j < 3; ++j) {
    int sg = j * 256 + tid;
    int kk2 = sg >> 6, nl = (sg >> 2) & 15, q = sg & 3;
    int qp = q ^ ((nl >> 1) & 3);
    e[j] = nl * KDIM + kk2 * 64 + qp * 16;
  }

  const int off0 = col * 64 + ((g * 8) ^ (((col >> 1) & 3) << 4));
  const float kinv = INVSCALE * LOG2E;

  auto COMPUTE = [&](int t) {
    const char* Bb = &Bsm[t & 1][0];
    const char* B0 = Bb + off0;
    const char* B1 = Bb + (off0 ^ 32);
    f32x4 acc0 = {0.f, 0.f, 0.f, 0.f}, acc1 = {0.f, 0.f, 0.f, 0.f};
    #pragma unroll
    for (int kk = 0; kk < 24; ++kk) {
      long b = *(const long*)(((kk & 1) ? B1 : B0) + (kk >> 1) * 1024);
      acc0 = __builtin_amdgcn_mfma_f32_16x16x32_fp8_fp8(a0[kk], b, acc0, 0, 0, 0);
      acc1 = __builtin_amdgcn_mfma_f32_16x16x32_fp8_fp8(a1[kk], b, acc1, 0, 0, 0);
    }
    const float bias2 = biasS[t * 16 + col];
    #pragma unroll
    for (int rr = 0; rr < 4; ++rr) {
      s[rr]     += exp2f(fmaf(acc0[rr], kinv, bias2));
      s[rr + 4] += exp2f(fmaf(acc1[rr], kinv, bias2));
    }
  };

  if constexpr (WM8) {
    auto STAGE = [&](int buf, int tt) {
      const char* src = Wm8 + (size_t)(nbeg + tt * 16) * KDIM;
      char* dst = &Bsm[buf][0] + wave * 1024;
      #pragma unroll
      for (int j = 0; j < 3; ++j) {
        __builtin_amdgcn_global_load_lds((glds_g*)(src + e[j]),
                                         (glds_l*)(dst + j * 4096), 16, 0, 0);
      }
    };
    STAGE(0, 0);
    asm volatile("s_waitcnt lgkmcnt(0)" ::: "memory");   // bias ds_writes done
    __builtin_amdgcn_s_barrier();
    for (int t = 0; t < NTILE; ++t) {
      int tn = (t + 1 < NTILE) ? t + 1 : 0;
      STAGE((t + 1) & 1, tn);                            // prefetch next tile
      asm volatile("s_waitcnt vmcnt(3)" ::: "memory");   // current tile staged
      __builtin_amdgcn_s_barrier();
      __builtin_amdgcn_sched_barrier(0);
      __builtin_amdgcn_s_setprio(1);
      COMPUTE(t);
      __builtin_amdgcn_s_setprio(0);
      __builtin_amdgcn_sched_barrier(0);
      __builtin_amdgcn_s_barrier();                      // all reads of cur done
    }
  } else {
    // fallback: serial staging from f32 Wm with inline fp8 cvt (x16), same layout
    __syncthreads();
    for (int t = 0; t < NTILE; ++t) {
      #pragma unroll
      for (int j = 0; j < 3; ++j) {
        int sg = j * 256 + tid;
        int n = nbeg + t * 16 + ((sg >> 2) & 15);
        int kk2 = sg >> 6, q = sg & 3;
        int qp = q ^ ((((sg >> 2) & 15) >> 1) & 3);
        int koff = kk2 * 64 + qp * 16;
        int4 o = {0, 0, 0, 0};
        if (n < NVOC) {
          const float* wp = Wm + (size_t)n * KDIM + koff;
          float4 f0 = ((const float4*)wp)[0], f1 = ((const float4*)wp)[1];
          float4 f2 = ((const float4*)wp)[2], f3 = ((const float4*)wp)[3];
          o.x = pk4_fp8(f0, WMSCALE); o.y = pk4_fp8(f1, WMSCALE);
          o.z = pk4_fp8(f2, WMSCALE); o.w = pk4_fp8(f3, WMSCALE);
        }
        *(int4*)(&Bsm[0][0] + sg * 16) = o;
      }
      __syncthreads();
      COMPUTE(t);
      __syncthreads();
    }
  }

  // combine the 16 col-owner lanes per row, write per-chunk partial sums
  #pragma unroll
  for (int i = 0; i < 8; ++i) {
    float v = s[i];
    v += __shfl_xor(v, 1);
    v += __shfl_xor(v, 2);
    v += __shfl_xor(v, 4);
    v += __shfl_xor(v, 8);
    s[i] = v;
  }
  if (col == 0) {
    #pragma unroll
    for (int mblk = 0; mblk < 2; ++mblk)
      #pragma unroll
      for (int rr = 0; rr < 4; ++rr) {
        int tok = arow0 + mblk * 16 + g * 4 + rr;
        psum[tok * NCHUNK + chunk] = s[mblk * 4 + rr];
      }
  }
}

// ---------------- fused tail: tag (0..312) | gold (313..1336) | embed (1337..1368) ----
__global__ __launch_bounds__(256) void k_tail(
    const unsigned short* __restrict__ Avid,
    const float* __restrict__ Wt, const float* __restrict__ bt,
    const float* __restrict__ ylab,
    const float* __restrict__ title, const int* __restrict__ lab,
    const float* __restrict__ Wm, const float* __restrict__ bm,
    const float* __restrict__ video,
    const float* __restrict__ Wh, const float* __restrict__ bh,
    float* __restrict__ out_sig, float* __restrict__ tagSum,
    float* __restrict__ gold, float* __restrict__ out_emb) {
  __shared__ __align__(1024) char smem[49664];
  const int bid = blockIdx.x, tid = threadIdx.x;
  const int wave = tid >> 6, lane = tid & 63, g = lane >> 4, col = lane & 15;

  if (bid < TAG_BLKS) {
    // ---- tag head: 2 ntiles/block, Wt staged coalesced -> bf16 LDS ----
    unsigned short* Bt = (unsigned short*)smem;       // [2][24 KiB]
    float* wsum = (float*)(smem + 49152);
    #pragma unroll
    for (int j = 0; j < 12; ++j) {
      int sg = j * 256 + tid;
      int tt = (j >= 6) ? 1 : 0;
      int sgl = sg - tt * 1536;
      int kk = sgl >> 6, c = (sgl & 63) >> 2, gg = sgl & 3;
      int n = (bid * 2 + tt) * 16 + c;
      bf16x8 o = {};
      if (n < NTAG) {
        const float* wp = Wt + (size_t)n * KDIM + kk * 32 + gg * 8;
        float4 f0 = ((const float4*)wp)[0], f1 = ((const float4*)wp)[1];
        o[0] = (short)f2bf(f0.x); o[1] = (short)f2bf(f0.y);
        o[2] = (short)f2bf(f0.z); o[3] = (short)f2bf(f0.w);
        o[4] = (short)f2bf(f1.x); o[5] = (short)f2bf(f1.y);
        o[6] = (short)f2bf(f1.z); o[7] = (short)f2bf(f1.w);
      }
      *(bf16x8*)((char*)Bt + sg * 16) = o;
    }
    __syncthreads();

    const int ntile = bid * 2 + (wave >> 1), mhalf = wave & 1;
    float lacc = 0.f;
    if (ntile < 625) {
      bf16x8 a[24];
      #pragma unroll
      for (int kk = 0; kk < 24; ++kk)
        a[kk] = *(const bf16x8*)(Avid + (size_t)(mhalf * 16 + col) * KDIM + kk * 32 + g * 8);
      const char* Bb = (const char*)Bt + (wave >> 1) * 24576 + col * 64 + g * 16;
      f32x4 acc = {0.f, 0.f, 0.f, 0.f};
      #pragma unroll
      for (int kk = 0; kk < 24; ++kk) {
        bf16x8 b = *(const bf16x8*)(Bb + kk * 1024);
        acc = __builtin_amdgcn_mfma_f32_16x16x32_bf16(a[kk], b, acc, 0, 0, 0);
      }
      const int nc = ntile * 16 + col;
      if (nc < NTAG) {
        const float bias = bt[nc];
        #pragma unroll
        for (int rr = 0; rr < 4; ++rr) {
          int brow = mhalf * 16 + g * 4 + rr;
          float x = acc[rr] + bias;
          out_sig[(size_t)brow * NTAG + nc] = 1.f / (1.f + __expf(-x));
          float y = ylab[(size_t)brow * NTAG + nc];
          lacc += fmaxf(x, 0.f) - x * y + log1pf(__expf(-fabsf(x)));
        }
      }
    }
    #pragma unroll
    for (int m = 32; m; m >>= 1) lacc += __shfl_xor(lacc, m);
    if (lane == 0) wsum[wave] = lacc;
    __syncthreads();
    if (tid == 0) atomicAdd(tagSum, wsum[0] + wsum[1] + wsum[2] + wsum[3]);

  } else if (bid < TAG_BLKS + GOLD_BLKS) {
    // ---- gold logit per token (f32 exact) ----
    int tok = (bid - TAG_BLKS) * 4 + wave;
    int l = lab[tok];
    float acc = 0.f;
    #pragma unroll
    for (int j = 0; j < 12; ++j) {
      int k = j * 64 + lane;
      acc += title[(size_t)tok * KDIM + k] * Wm[(size_t)l * KDIM + k];
    }
    #pragma unroll
    for (int m = 32; m; m >>= 1) acc += __shfl_xor(acc, m);
    if (lane == 0) gold[tok] = acc + bm[l];

  } else {
    // ---- embedding head (f32 exact) ----
    float* feat = (float*)smem;
    float* red = (float*)(smem + 49152);
    const int b = bid - TAG_BLKS - GOLD_BLKS;
    #pragma unroll
    for (int j = 0; j < 6; ++j) {
      int k = j * 256 + tid;
      feat[k] = (k < KDIM) ? video[(size_t)b * KDIM + k]
                           : title[(size_t)b * 128 * KDIM + (k - KDIM)];
    }
    __syncthreads();
    float acc = bh[tid];
    #pragma unroll 8
    for (int k = 0; k < 1536; k += 4) {
      float4 w = *(const float4*)(Wh + (size_t)tid * 1536 + k);
      acc += w.x * feat[k] + w.y * feat[k + 1] + w.z * feat[k + 2] + w.w * feat[k + 3];
    }
    float ss = acc * acc;
    #pragma unroll
    for (int m = 32; m; m >>= 1) ss += __shfl_xor(ss, m);
    if (lane == 0) red[wave] = ss;
    __syncthreads();
    float nrm = sqrtf(red[0] + red[1] + red[2] + red[3]);
    float scale = 1.f / fmaxf(nrm, 1e-12f);
    out_emb[(size_t)b * HID + tid] = acc * scale;
  }
}

// ---------------- finalize losses ----------------
__global__ __launch_bounds__(256) void k_final(
    const float* __restrict__ psum, const float* __restrict__ gold,
    const int* __restrict__ lab, const float* __restrict__ tagSum,
    float* __restrict__ out) {
  __shared__ float red[4];
  const int tid = threadIdx.x, wave = tid >> 6, lane = tid & 63;
  if (tid == 0) out[OUT_LTAG] = tagSum[0] / 320000.f;

  float lm = 0.f;
  for (int tok = tid; tok < NTOK; tok += 256) {
    float S = 0.f;
    #pragma unroll
    for (int c = 0; c < NCHUNK; ++c) S += psum[tok * NCHUNK + c];
    float lse = M0 + logf(S);
    if (lab[tok] != 0) lm += lse - gold[tok];
  }
  #pragma unroll
  for (int m = 32; m; m >>= 1) lm += __shfl_xor(lm, m);
  if (lane == 0) red[wave] = lm;
  __syncthreads();
  if (tid == 0) out[OUT_LMLM] = red[0] + red[1] + red[2] + red[3];
}

extern "C" void kernel_launch(void* const* d_in, const int* in_sizes, int n_in,
                              void* d_out, int out_size, void* d_ws, size_t ws_size,
                              hipStream_t stream) {
  const float* video = (const float*)d_in[0];
  const float* title = (const float*)d_in[1];
  const float* ylab  = (const float*)d_in[2];
  const int*   lab   = (const int*)d_in[3];
  const float* Wt = (const float*)d_in[4];
  const float* bt = (const float*)d_in[5];
  const float* Wm = (const float*)d_in[6];
  const float* bm = (const float*)d_in[7];
  const float* Wh = (const float*)d_in[8];
  const float* bh = (const float*)d_in[9];
  float* out = (float*)d_out;
  char* ws = (char*)d_ws;

  char* wsA8   = ws + WS_A;
  unsigned short* wsAvid = (unsigned short*)(ws + WS_AVID);
  float* wsPsum = (float*)(ws + WS_PSUM);
  float* wsGold = (float*)(ws + WS_GOLD);
  float* wsTagl = (float*)(ws + WS_TAGL);
  char* wsWm8  = ws + WS_WM8;

  const bool useWm8 = ws_size >= WS_NEED;

  k_conv<<<9471, 256, 0, stream>>>(title, video, Wm, wsA8, wsAvid, wsWm8, wsTagl);
  if (useWm8)
    k_mlm<true><<<768, 256, 0, stream>>>(wsA8, Wm, wsWm8, bm, wsPsum);
  else
    k_mlm<false><<<768, 256, 0, stream>>>(wsA8, Wm, wsWm8, bm, wsPsum);
  k_tail<<<TAG_BLKS + GOLD_BLKS + EMB_BLKS, 256, 0, stream>>>(
      wsAvid, Wt, bt, ylab, title, lab, Wm, bm, video, Wh, bh,
      out, wsTagl, wsGold, out + OUT_EMB);
  k_final<<<1, 256, 0, stream>>>(wsPsum, wsGold, lab, wsTagl, out);
}